// Round 7
// baseline (586.234 us; speedup 1.0000x reference)
//
#include <hip/hip_runtime.h>

// B=2, S=2048, D=1024, H=16, DK=64.  I/O fp32; internal MFMA pipeline bf16.
typedef __bf16 bf16x8 __attribute__((ext_vector_type(8)));
typedef float  f32x4  __attribute__((ext_vector_type(4)));
typedef short  s16x2  __attribute__((ext_vector_type(2)));

#define AS1 __attribute__((address_space(1)))
#define AS3 __attribute__((address_space(3)))

__device__ __forceinline__ void g2l16(const void* g, void* l) {
  __builtin_amdgcn_global_load_lds((AS1 void*)g, (AS3 void*)l, 16, 0, 0);
}
#define MFMA16(a, b, c) __builtin_amdgcn_mfma_f32_16x16x32_bf16(a, b, c, 0, 0, 0)

__device__ __forceinline__ unsigned pack_bf16(float a, float b) {
  union { __bf16 h[2]; unsigned u; } p;
  p.h[0] = (__bf16)a; p.h[1] = (__bf16)b;
  return p.u;
}

// ---------------- fused prep: cvt x3 | mask -> KEEP bitmask | transpose_w4 ----------------
__global__ __launch_bounds__(256) void prep(const float* __restrict__ inQ,
    const float* __restrict__ inK, const float* __restrict__ inV,
    const int* __restrict__ mask,
    const float* __restrict__ W0, const float* __restrict__ W1,
    const float* __restrict__ W2, const float* __restrict__ W3,
    __bf16* __restrict__ Xq, __bf16* __restrict__ Xk, __bf16* __restrict__ Xv,
    unsigned long long* __restrict__ bits, __bf16* __restrict__ Wt) {
  __shared__ __bf16 tile[64][65];
  const int blk = blockIdx.x;
  if (blk < 6144) {
    const int z = blk >> 11, bx = blk & 2047;
    const float* src = z == 0 ? inQ : (z == 1 ? inK : inV);
    __bf16* dst = z == 0 ? Xq : (z == 1 ? Xk : Xv);
    size_t base = ((size_t)bx * 256 + threadIdx.x) * 8;
    float4 f0 = *(const float4*)(src + base);
    float4 f1 = *(const float4*)(src + base + 4);
    bf16x8 o;
    o[0] = (__bf16)f0.x; o[1] = (__bf16)f0.y; o[2] = (__bf16)f0.z; o[3] = (__bf16)f0.w;
    o[4] = (__bf16)f1.x; o[5] = (__bf16)f1.y; o[6] = (__bf16)f1.z; o[7] = (__bf16)f1.w;
    *(bf16x8*)(dst + base) = o;
  } else if (blk < 10240) {
    const int lane = threadIdx.x & 63, w = threadIdx.x >> 6;
    const int base = (blk - 6144) * 2048 + w * 512;
#pragma unroll
    for (int it = 0; it < 8; ++it) {
      int i = base + it * 64 + lane;
      // KEEP bit (mask==0): attn zeroes p via sign-mask AND on packed bf16
      unsigned long long bb = __ballot(mask[i] == 0);
      if (lane == 0) bits[i >> 6] = bb;
    }
  } else {
    const int idx = blk - 10240;
    const int z = idx >> 8, rem = idx & 255, bx = rem & 15, by = rem >> 4;
    const float* srcs[4] = {W0, W1, W2, W3};
    const float* src = srcs[z];
    __bf16* dst = Wt + (size_t)z * 1024 * 1024;
    int cb = bx * 64, rb = by * 64;
    for (int i = threadIdx.x; i < 4096; i += 256) {
      int r = i >> 6, c = i & 63;
      tile[r][c] = (__bf16)src[(size_t)(rb + r) * 1024 + cb + c];
    }
    __syncthreads();
    for (int i = threadIdx.x; i < 4096; i += 256) {
      int c = i >> 6, r = i & 63;
      dst[(size_t)(cb + c) * 1024 + rb + r] = tile[r][c];
    }
  }
}

// ---------------- QKV projection GEMM, 128x128 tile, BK=32 ----------------
// z=0: Q scaled by log2e/8.  z=1: K.  z=2: V -> V^T [BH][DK][S] via LDS restage,
// with per-32-chunk t-permutation slot(t)=8*((t>>2)&3)+2*(t&3)+((t>>4)&1) so that
// attn's exp2 outputs (packed as (j0,j1) pairs) feed the PV A-fragment directly.
__global__ __launch_bounds__(256) void qkv_gemm(const __bf16* __restrict__ Xq,
    const __bf16* __restrict__ Xk, const __bf16* __restrict__ Xv,
    const __bf16* __restrict__ Wt, __bf16* __restrict__ Qb,
    __bf16* __restrict__ Kb, __bf16* __restrict__ Vtb) {
  __shared__ __align__(16) __bf16 sh[8192];   // As | Bs; reused as 64x128 transpose buf
  __bf16* As = sh;
  __bf16* Bs = sh + 4096;
  const int z = blockIdx.z;
  const __bf16* X = z == 0 ? Xq : (z == 1 ? Xk : Xv);
  const __bf16* W = Wt + (size_t)z * 1048576;
  const float scale = z == 0 ? 0.125f * 1.44269504088896f : 1.f;
  const int t = threadIdx.x;
  const int lane = t & 63, w = t >> 6;
  const int lane15 = lane & 15, quad = lane >> 4;
  const int wm = (w >> 1) * 64, wn = (w & 1) * 64;
  const int mBase = blockIdx.y * 128, nBase = blockIdx.x * 128;
  const int c1 = t, c2 = t + 256;
  f32x4 acc[4][4] = {};
  for (int kt = 0; kt < 1024; kt += 32) {
    __syncthreads();
    g2l16(X + (size_t)(mBase + (c1 >> 2)) * 1024 + kt + (c1 & 3) * 8, As + c1 * 8);
    g2l16(X + (size_t)(mBase + (c2 >> 2)) * 1024 + kt + (c2 & 3) * 8, As + c2 * 8);
    g2l16(W + (size_t)(nBase + (c1 >> 2)) * 1024 + kt + (c1 & 3) * 8, Bs + c1 * 8);
    g2l16(W + (size_t)(nBase + (c2 >> 2)) * 1024 + kt + (c2 & 3) * 8, Bs + c2 * 8);
    __builtin_amdgcn_s_waitcnt(0);
    __syncthreads();
    bf16x8 a[4], b[4];
#pragma unroll
    for (int i = 0; i < 4; i++) a[i] = *(const bf16x8*)&As[(wm + i * 16 + lane15) * 32 + quad * 8];
#pragma unroll
    for (int j = 0; j < 4; j++) b[j] = *(const bf16x8*)&Bs[(wn + j * 16 + lane15) * 32 + quad * 8];
#pragma unroll
    for (int i = 0; i < 4; i++)
#pragma unroll
      for (int j = 0; j < 4; j++)
        acc[i][j] = MFMA16(a[i], b[j], acc[i][j]);
  }
  if (z != 2) {
    __bf16* Y = z == 0 ? Qb : Kb;
#pragma unroll
    for (int i = 0; i < 4; i++)
#pragma unroll
      for (int j = 0; j < 4; j++)
#pragma unroll
        for (int r = 0; r < 4; r++) {
          int mg = mBase + wm + i * 16 + quad * 4 + r;
          int ng = nBase + wn + j * 16 + lane15;
          int b_ = mg >> 11, s_ = mg & 2047, h_ = ng >> 6, d_ = ng & 63;
          Y[(((size_t)(b_ * 16 + h_)) * 2048 + s_) * 64 + d_] = (__bf16)(acc[i][j][r] * scale);
        }
  } else {
    const int s0 = mBase & 2047;
    const int bhBase = (mBase >> 11) * 16 + (nBase >> 6);
#pragma unroll
    for (int half = 0; half < 2; ++half) {
      __syncthreads();
      if ((w & 1) == half) {
#pragma unroll
        for (int i = 0; i < 4; i++)
#pragma unroll
          for (int j = 0; j < 4; j++)
#pragma unroll
            for (int r = 0; r < 4; r++) {
              int nl = j * 16 + lane15;
              int ml = wm + i * 16 + quad * 4 + r;
              // within-32 t-permutation to match attn's in-register P fragment
              int l5 = ml & 31;
              int mlp = (ml & 96) | ((((l5 >> 2) & 3) * 8) + ((l5 & 3) * 2) + ((l5 >> 4) & 1));
              sh[nl * 128 + (mlp ^ ((nl & 7) * 16))] = (__bf16)acc[i][j][r];
            }
      }
      __syncthreads();
      const int row = t >> 2, c0 = (t & 3) * 32;
      const int xr = (row & 7) * 16;
      const int b0 = row * 128 + (c0 ^ xr);
      const int b1 = row * 128 + ((c0 + 16) ^ xr);
      bf16x8 a0 = *(const bf16x8*)&sh[b0];
      bf16x8 a1 = *(const bf16x8*)&sh[b0 + 8];
      bf16x8 a2 = *(const bf16x8*)&sh[b1];
      bf16x8 a3 = *(const bf16x8*)&sh[b1 + 8];
      __bf16* dst = Vtb + (size_t)(bhBase + half) * 131072 + (size_t)row * 2048 + s0 + c0;
      *(bf16x8*)(dst)      = a0;
      *(bf16x8*)(dst + 8)  = a1;
      *(bf16x8*)(dst + 16) = a2;
      *(bf16x8*)(dst + 24) = a3;
    }
  }
}

// ---------------- output projection + fp32 residual, 64x128 tile ----------------
__global__ __launch_bounds__(256) void gemm_wo(const __bf16* __restrict__ X,
    const __bf16* __restrict__ Wt, const float* __restrict__ resid,
    float* __restrict__ Yf) {
  __shared__ __align__(16) __bf16 As[64 * 32];
  __shared__ __align__(16) __bf16 Bs[128 * 32];
  const int t = threadIdx.x;
  const int lane = t & 63, w = t >> 6;
  const int lane15 = lane & 15, quad = lane >> 4;
  const int wm = (w >> 1) * 32, wn = (w & 1) * 64;
  const int mBase = blockIdx.y * 64, nBase = blockIdx.x * 128;
  f32x4 acc[2][4] = {};
  for (int kt = 0; kt < 1024; kt += 32) {
    __syncthreads();
    g2l16(X  + (size_t)(mBase + (t >> 2)) * 1024 + kt + (t & 3) * 8, As + t * 8);
    g2l16(Wt + (size_t)(nBase + (t >> 2)) * 1024 + kt + (t & 3) * 8, Bs + t * 8);
    g2l16(Wt + (size_t)(nBase + ((t + 256) >> 2)) * 1024 + kt + (t & 3) * 8, Bs + (t + 256) * 8);
    __builtin_amdgcn_s_waitcnt(0);
    __syncthreads();
    bf16x8 a[2], b[4];
#pragma unroll
    for (int i = 0; i < 2; i++) a[i] = *(const bf16x8*)&As[(wm + i * 16 + lane15) * 32 + quad * 8];
#pragma unroll
    for (int j = 0; j < 4; j++) b[j] = *(const bf16x8*)&Bs[(wn + j * 16 + lane15) * 32 + quad * 8];
#pragma unroll
    for (int i = 0; i < 2; i++)
#pragma unroll
      for (int j = 0; j < 4; j++)
        acc[i][j] = MFMA16(a[i], b[j], acc[i][j]);
  }
#pragma unroll
  for (int i = 0; i < 2; i++)
#pragma unroll
    for (int j = 0; j < 4; j++)
#pragma unroll
      for (int r = 0; r < 4; r++) {
        int mg = mBase + wm + i * 16 + quad * 4 + r;
        int ng = nBase + wn + j * 16 + lane15;
        size_t idx = (size_t)mg * 1024 + ng;
        Yf[idx] = acc[i][j][r] + resid[idx];
      }
}

// ---------------- flash attention: 16x16, 2 t-tiles per body (32 barriers) ----------------
// XCD swizzle: all 32 q-blocks of one bh share one XCD -> K/V L2-resident (FETCH 14MB).
// Body m (tiles T=2m,T+1): barrier | stage K(T+4,T+5)->Kslot{T&3,(T+1)&3}, V(T,T+1)->
// Vslot{T&3,(T+1)&3} | mask uint2 | PV(T-4,T-3) | exp2(T-2,T-1)->pa | QK(T,T+1)->st |
// vreg(T-2,T-1) | kreg(T+2,T+3).  Slot liveness: body writes {0,1} while reading {2,3}
// (alternating); K/V separate arrays.  Single-set registers; ordering via data deps
// (PV before exp2 before QK before prefetch).  All indices compile-time (rule #20).
__global__ __launch_bounds__(256, 4) void attn_kernel(const __bf16* __restrict__ Q,
    const __bf16* __restrict__ Kp, const __bf16* __restrict__ Vt,
    const unsigned* __restrict__ mbits, __bf16* __restrict__ ctx) {
  __shared__ __align__(16) __bf16 Qs[64 * 64];     // 8KB [q][dk]
  __shared__ __align__(16) __bf16 Ks[4][32 * 64];  // 16KB [t][dk]
  __shared__ __align__(16) __bf16 Vs[4][64 * 32];  // 16KB [d][t-permuted]
  const int t = threadIdx.x, lane = t & 63, w = t >> 6;
  const int l15 = lane & 15, quad = lane >> 4;
  // XCD-aware swizzle: id%8 = XCD; give each XCD 4 whole bh's (32 q-tiles each)
  const int id = blockIdx.x + (blockIdx.y << 5);
  const int iix = id >> 3;
  const int bh = (id & 7) * 4 + (iix >> 5);
  const int qBase = (iix & 31) * 64;
  const int b = bh >> 4, h = bh & 15;
  const size_t qko = (size_t)bh * 2048 * 64;
  const size_t vko = (size_t)bh * 64 * 2048;
  const int srow8 = lane >> 3, sch8 = (lane & 7) ^ srow8;
  const int srow16 = lane >> 2, sch4 = (lane & 3) ^ ((lane >> 3) & 3);
  const int stOff = w * 512 + lane * 8;
  const __bf16* kSrc = Kp + qko + (size_t)(w * 8 + srow8) * 64 + sch8 * 8;
  const __bf16* vSrc = Vt + vko + (size_t)(w * 16 + srow16) * 2048 + sch4 * 8;
  __bf16* KsF = &Ks[0][0];
  __bf16* VsF = &Vs[0][0];
  g2l16(Q + qko + (size_t)(qBase + w * 8 + srow8) * 64 + sch8 * 8,       Qs + w * 512 + lane * 8);
  g2l16(Q + qko + (size_t)(qBase + (w + 4) * 8 + srow8) * 64 + sch8 * 8, Qs + (w + 4) * 512 + lane * 8);
  // prologue: K tiles 0..3 into slots 0..3 (V tiles 0,1 staged at body 0)
  g2l16(kSrc,            KsF + 0 * 2048 + stOff);
  g2l16(kSrc + 1 * 2048, KsF + 1 * 2048 + stOff);
  g2l16(kSrc + 2 * 2048, KsF + 2 * 2048 + stOff);
  g2l16(kSrc + 3 * 2048, KsF + 3 * 2048 + stOff);
  const __bf16* kStage = kSrc + 4 * 2048;
  const __bf16* vStage = vSrc;
  const size_t mIdx = ((size_t)b * 2048 + qBase + w * 16 + l15) * 64;
  const unsigned* mbp = mbits + mIdx;
  uint2 mC = *(const uint2*)(mbp); mbp += 2;   // masks tiles 0,1
  uint2 mP = mC;
  __builtin_amdgcn_s_waitcnt(0);
  __syncthreads();
  bf16x8 qb0, qb1;
  {
    const int r = w * 16 + l15, s = r & 7;
    qb0 = *(const bf16x8*)&Qs[r * 64 + ((quad ^ s) * 8)];
    qb1 = *(const bf16x8*)&Qs[r * 64 + (((4 + quad) ^ s) * 8)];
  }
  // per-thread LDS fragment base pointers (slot selected via constant immediate offset)
  const int sA = l15 & 7, trB = 16 + l15, sB = trB & 7;
  const __bf16* pKA0 = KsF + l15 * 64 + ((quad ^ sA) * 8);
  const __bf16* pKA1 = KsF + l15 * 64 + (((4 + quad) ^ sA) * 8);
  const __bf16* pKB0 = KsF + trB * 64 + ((quad ^ sB) * 8);
  const __bf16* pKB1 = KsF + trB * 64 + (((4 + quad) ^ sB) * 8);
  const int dr0 = l15,      dr1 = 16 + l15, dr2 = 32 + l15, dr3 = 48 + l15;
  const __bf16* pV0 = VsF + dr0 * 32 + ((quad ^ ((dr0 >> 1) & 3)) * 8);
  const __bf16* pV1 = VsF + dr1 * 32 + ((quad ^ ((dr1 >> 1) & 3)) * 8);
  const __bf16* pV2 = VsF + dr2 * 32 + ((quad ^ ((dr2 >> 1) & 3)) * 8);
  const __bf16* pV3 = VsF + dr3 * 32 + ((quad ^ ((dr3 >> 1) & 3)) * 8);
  bf16x8 kr0[2][2], kr1[2][2];   // K frags for tiles (T, T+1) of current body
  kr0[0][0] = *(const bf16x8*)(pKA0);
  kr0[0][1] = *(const bf16x8*)(pKA1);
  kr0[1][0] = *(const bf16x8*)(pKB0);
  kr0[1][1] = *(const bf16x8*)(pKB1);
  kr1[0][0] = *(const bf16x8*)(pKA0 + 2048);
  kr1[0][1] = *(const bf16x8*)(pKA1 + 2048);
  kr1[1][0] = *(const bf16x8*)(pKB0 + 2048);
  kr1[1][1] = *(const bf16x8*)(pKB1 + 2048);
  bf16x8 ones;
#pragma unroll
  for (int i = 0; i < 8; i++) ones[i] = (__bf16)1.0f;
  f32x4 o[4] = {};
  f32x4 ol = {};
  f32x4 st0[2] = {}, st1[2] = {};
  bf16x8 pa0 = {}, pa1 = {};
  bf16x8 vr0[4] = {}, vr1[4] = {};

#define QKT(KR, ST)                                                                 \
  { f32x4 zz = {0.f, 0.f, 0.f, 0.f};                                                \
    zz    = MFMA16(KR[0][0], qb0, zz);                                              \
    ST[0] = MFMA16(KR[0][1], qb1, zz);                                              \
    f32x4 zy = {0.f, 0.f, 0.f, 0.f};                                                \
    zy    = MFMA16(KR[1][0], qb0, zy);                                              \
    ST[1] = MFMA16(KR[1][1], qb1, zy); }

#define PVT(PA, VR)                                                                 \
  { ol   = MFMA16(PA, ones,  ol);                                                   \
    o[0] = MFMA16(PA, VR[0], o[0]);                                                 \
    o[1] = MFMA16(PA, VR[1], o[1]);                                                 \
    o[2] = MFMA16(PA, VR[2], o[2]);                                                 \
    o[3] = MFMA16(PA, VR[3], o[3]); }

#define EXPBLK(ST, MW, PA)                                                          \
  { const unsigned msh = (MW) >> (quad * 4);                                        \
    union { unsigned u[4]; bf16x8 v; } pk;                                          \
    _Pragma("unroll")                                                               \
    for (int r = 0; r < 4; r++) {                                                   \
      float e0 = __builtin_amdgcn_exp2f(ST[0][r]);                                  \
      float e1 = __builtin_amdgcn_exp2f(ST[1][r]);                                  \
      union { unsigned u; s16x2 s; } mc;                                            \
      mc.u = msh << (15 - r);                                                       \
      mc.s = mc.s >> 15;                                                            \
      pk.u[r] = pack_bf16(e0, e1) & mc.u;                                           \
    }                                                                               \
    PA = pk.v; }

#define KPF(KR, SL)                                                                 \
  { KR[0][0] = *(const bf16x8*)(pKA0 + (SL) * 2048);                                \
    KR[0][1] = *(const bf16x8*)(pKA1 + (SL) * 2048);                                \
    KR[1][0] = *(const bf16x8*)(pKB0 + (SL) * 2048);                                \
    KR[1][1] = *(const bf16x8*)(pKB1 + (SL) * 2048); }

#define VPF(VR, SL)                                                                 \
  { VR[0] = *(const bf16x8*)(pV0 + (SL) * 2048);                                    \
    VR[1] = *(const bf16x8*)(pV1 + (SL) * 2048);                                    \
    VR[2] = *(const bf16x8*)(pV2 + (SL) * 2048);                                    \
    VR[3] = *(const bf16x8*)(pV3 + (SL) * 2048); }

// WS0/WS1: write slots this body (K tiles T+4,T+5 and V tiles T,T+1);
// RS0/RS1: read slots (kreg tiles T+2,T+3; vreg tiles T-2,T-1 — same slots).
#define BODY2(DO_PV, DO_EXP, DO_KST, DO_KPF, DO_MLD, WS0, WS1, RS0, RS1)            \
  {                                                                                 \
    __syncthreads();                                                                \
    if (DO_KST) {                                                                   \
      g2l16(kStage,        KsF + (WS0) * 2048 + stOff);                             \
      g2l16(kStage + 2048, KsF + (WS1) * 2048 + stOff);                             \
      kStage += 4096;                                                               \
    }                                                                               \
    g2l16(vStage,      VsF + (WS0) * 2048 + stOff);                                 \
    g2l16(vStage + 32, VsF + (WS1) * 2048 + stOff);                                 \
    vStage += 64;                                                                   \
    uint2 mNew = mC;                                                                \
    if (DO_MLD) { mNew = *(const uint2*)(mbp); mbp += 2; }                          \
    if (DO_PV) { PVT(pa0, vr0); PVT(pa1, vr1); }                                    \
    if (DO_EXP) { EXPBLK(st0, mP.x, pa0); EXPBLK(st1, mP.y, pa1); }                 \
    QKT(kr0, st0);                                                                  \
    QKT(kr1, st1);                                                                  \
    if (DO_EXP) { VPF(vr0, RS0); VPF(vr1, RS1); }                                   \
    if (DO_KPF) { KPF(kr0, RS0); KPF(kr1, RS1); }                                   \
    mP = mC; mC = mNew;                                                             \
  }

  BODY2(0, 0, 1, 1, 1, 0, 1, 2, 3);   // m=0
  BODY2(0, 1, 1, 1, 1, 2, 3, 0, 1);   // m=1
#pragma unroll 1
  for (int m = 2; m < 30; m += 2) {
    BODY2(1, 1, 1, 1, 1, 0, 1, 2, 3);
    BODY2(1, 1, 1, 1, 1, 2, 3, 0, 1);
  }
  BODY2(1, 1, 0, 1, 1, 0, 1, 2, 3);   // m=30: no K stage
  BODY2(1, 1, 0, 0, 0, 2, 3, 0, 1);   // m=31: no K stage/kpf/mask-load
#undef BODY2

  // epilogue: PV(60,61); exp2(62,63); vreg(62,63); PV(62,63)
  __syncthreads();                     // drain V stage of tiles 62,63 (body 31)
  PVT(pa0, vr0); PVT(pa1, vr1);        // PV(60,61)
  EXPBLK(st0, mP.x, pa0);              // exp2(62) — mP = masks(62,63)
  EXPBLK(st1, mP.y, pa1);              // exp2(63)
  VPF(vr0, 2); VPF(vr1, 3);            // V tiles 62,63 (slots 2,3)
  PVT(pa0, vr0); PVT(pa1, vr1);        // PV(62,63)
#undef QKT
#undef PVT
#undef EXPBLK
#undef KPF
#undef VPF

#pragma unroll
  for (int r = 0; r < 4; r++) {
    float inv = 1.f / ol[r];
    int qg = qBase + w * 16 + quad * 4 + r;
    size_t base = ((size_t)b * 2048 + qg) * 1024 + h * 64;
#pragma unroll
    for (int j = 0; j < 4; j++)
      ctx[base + j * 16 + l15] = (__bf16)(o[j][r] * inv);
  }
}

// ---------------- LayerNorm over D=1024 per row (fp32) ----------------
__global__ __launch_bounds__(256) void ln_kernel(const float* __restrict__ X,
    const float* __restrict__ gamma, const float* __restrict__ beta,
    float* __restrict__ out) {
  __shared__ float red[8];
  const int t = threadIdx.x;
  const size_t row = blockIdx.x;
  const float* xr = X + row * 1024;
  float4 x = *(const float4*)(xr + t * 4);
  float s = x.x + x.y + x.z + x.w;
  float s2 = x.x * x.x + x.y * x.y + x.z * x.z + x.w * x.w;
#pragma unroll
  for (int off = 1; off < 64; off <<= 1) { s += __shfl_xor(s, off); s2 += __shfl_xor(s2, off); }
  if ((t & 63) == 0) { red[t >> 6] = s; red[4 + (t >> 6)] = s2; }
  __syncthreads();
  float S1 = red[0] + red[1] + red[2] + red[3];
  float S2 = red[4] + red[5] + red[6] + red[7];
  float mu = S1 * (1.f / 1024.f);
  float var = S2 * (1.f / 1024.f) - mu * mu;
  float rs = rsqrtf(var + 1e-5f);
  float4 g = *(const float4*)(gamma + t * 4);
  float4 bb = *(const float4*)(beta + t * 4);
  float4 y;
  y.x = (x.x - mu) * rs * g.x + bb.x;
  y.y = (x.y - mu) * rs * g.y + bb.y;
  y.z = (x.z - mu) * rs * g.z + bb.z;
  y.w = (x.w - mu) * rs * g.w + bb.w;
  *(float4*)(out + row * 1024 + t * 4) = y;
}

extern "C" void kernel_launch(void* const* d_in, const int* in_sizes, int n_in,
                              void* d_out, int out_size, void* d_ws, size_t ws_size,
                              hipStream_t stream) {
  const float* inQ  = (const float*)d_in[0];
  const float* inK  = (const float*)d_in[1];
  const float* inV  = (const float*)d_in[2];
  const int*   mask = (const int*)d_in[3];
  const float* WQ   = (const float*)d_in[4];
  const float* WK   = (const float*)d_in[5];
  const float* WV   = (const float*)d_in[6];
  const float* WO   = (const float*)d_in[7];
  const float* gamma = (const float*)d_in[8];
  const float* beta  = (const float*)d_in[9];

  const size_t MB = 1024 * 1024;
  char* ws = (char*)d_ws;
  __bf16* Xq  = (__bf16*)(ws);                    // 8 MB each
  __bf16* Xk  = (__bf16*)(ws + 8 * MB);
  __bf16* Xv  = (__bf16*)(ws + 16 * MB);
  __bf16* Qb  = (__bf16*)(ws + 24 * MB);          // [BH][S][DK]
  __bf16* Kb  = (__bf16*)(ws + 32 * MB);
  __bf16* Vtb = (__bf16*)(ws + 48 * MB);          // [BH][DK][S] (t-permuted per 32)
  __bf16* Wt  = (__bf16*)(ws + 56 * MB);          // 4x 2MB bf16^T weights
  unsigned long long* mbits = (unsigned long long*)(ws + 64 * MB);  // 1 MB (KEEP bits)
  __bf16* ctx  = Xq;                              // reuse
  float*  outp = (float*)(ws + 8 * MB);           // reuse Xk+Xv

  prep<<<dim3(11264), 256, 0, stream>>>(inQ, inK, inV, mask, WQ, WK, WV, WO,
                                        Xq, Xk, Xv, mbits, Wt);
  qkv_gemm<<<dim3(8, 32, 3), 256, 0, stream>>>(Xq, Xk, Xv, Wt, Qb, Kb, Vtb);
  attn_kernel<<<dim3(32, 32), 256, 0, stream>>>(Qb, Kb, Vtb, (const unsigned*)mbits, ctx);
  gemm_wo<<<dim3(8, 64), 256, 0, stream>>>(ctx, Wt + 3 * 1048576, inQ, outp);
  ln_kernel<<<dim3(4096), 256, 0, stream>>>(outp, gamma, beta, (float*)d_out);
}

// Round 8
// 257.873 us; speedup vs baseline: 2.2733x; 2.2733x over previous
//
#include <hip/hip_runtime.h>

// B=2, S=2048, D=1024, H=16, DK=64.  I/O fp32; internal MFMA pipeline bf16.
typedef __bf16 bf16x8 __attribute__((ext_vector_type(8)));
typedef float  f32x4  __attribute__((ext_vector_type(4)));
typedef short  s16x2  __attribute__((ext_vector_type(2)));

#define AS1 __attribute__((address_space(1)))
#define AS3 __attribute__((address_space(3)))

__device__ __forceinline__ void g2l16(const void* g, void* l) {
  __builtin_amdgcn_global_load_lds((AS1 void*)g, (AS3 void*)l, 16, 0, 0);
}
#define MFMA16(a, b, c) __builtin_amdgcn_mfma_f32_16x16x32_bf16(a, b, c, 0, 0, 0)

__device__ __forceinline__ unsigned pack_bf16(float a, float b) {
  union { __bf16 h[2]; unsigned u; } p;
  p.h[0] = (__bf16)a; p.h[1] = (__bf16)b;
  return p.u;
}

// ---------------- fused prep: cvt x3 | mask -> KEEP bitmask | transpose_w4 ----------------
__global__ __launch_bounds__(256) void prep(const float* __restrict__ inQ,
    const float* __restrict__ inK, const float* __restrict__ inV,
    const int* __restrict__ mask,
    const float* __restrict__ W0, const float* __restrict__ W1,
    const float* __restrict__ W2, const float* __restrict__ W3,
    __bf16* __restrict__ Xq, __bf16* __restrict__ Xk, __bf16* __restrict__ Xv,
    unsigned long long* __restrict__ bits, __bf16* __restrict__ Wt) {
  __shared__ __bf16 tile[64][65];
  const int blk = blockIdx.x;
  if (blk < 6144) {
    const int z = blk >> 11, bx = blk & 2047;
    const float* src = z == 0 ? inQ : (z == 1 ? inK : inV);
    __bf16* dst = z == 0 ? Xq : (z == 1 ? Xk : Xv);
    size_t base = ((size_t)bx * 256 + threadIdx.x) * 8;
    float4 f0 = *(const float4*)(src + base);
    float4 f1 = *(const float4*)(src + base + 4);
    bf16x8 o;
    o[0] = (__bf16)f0.x; o[1] = (__bf16)f0.y; o[2] = (__bf16)f0.z; o[3] = (__bf16)f0.w;
    o[4] = (__bf16)f1.x; o[5] = (__bf16)f1.y; o[6] = (__bf16)f1.z; o[7] = (__bf16)f1.w;
    *(bf16x8*)(dst + base) = o;
  } else if (blk < 10240) {
    const int lane = threadIdx.x & 63, w = threadIdx.x >> 6;
    const int base = (blk - 6144) * 2048 + w * 512;
#pragma unroll
    for (int it = 0; it < 8; ++it) {
      int i = base + it * 64 + lane;
      // KEEP bit (mask==0): attn zeroes p via sign-mask AND on packed bf16
      unsigned long long bb = __ballot(mask[i] == 0);
      if (lane == 0) bits[i >> 6] = bb;
    }
  } else {
    const int idx = blk - 10240;
    const int z = idx >> 8, rem = idx & 255, bx = rem & 15, by = rem >> 4;
    const float* srcs[4] = {W0, W1, W2, W3};
    const float* src = srcs[z];
    __bf16* dst = Wt + (size_t)z * 1024 * 1024;
    int cb = bx * 64, rb = by * 64;
    for (int i = threadIdx.x; i < 4096; i += 256) {
      int r = i >> 6, c = i & 63;
      tile[r][c] = (__bf16)src[(size_t)(rb + r) * 1024 + cb + c];
    }
    __syncthreads();
    for (int i = threadIdx.x; i < 4096; i += 256) {
      int c = i >> 6, r = i & 63;
      dst[(size_t)(cb + c) * 1024 + rb + r] = tile[r][c];
    }
  }
}

// ---------------- QKV projection GEMM, 128x128 tile, BK=32 ----------------
// z=0: Q scaled by log2e/8.  z=1: K.  z=2: V -> V^T [BH][DK][S] via LDS restage,
// with per-32-chunk t-permutation slot(t)=8*((t>>2)&3)+2*(t&3)+((t>>4)&1) so that
// attn's exp2 outputs (packed as (j0,j1) pairs) feed the PV A-fragment directly.
__global__ __launch_bounds__(256) void qkv_gemm(const __bf16* __restrict__ Xq,
    const __bf16* __restrict__ Xk, const __bf16* __restrict__ Xv,
    const __bf16* __restrict__ Wt, __bf16* __restrict__ Qb,
    __bf16* __restrict__ Kb, __bf16* __restrict__ Vtb) {
  __shared__ __align__(16) __bf16 sh[8192];   // As | Bs; reused as 64x128 transpose buf
  __bf16* As = sh;
  __bf16* Bs = sh + 4096;
  const int z = blockIdx.z;
  const __bf16* X = z == 0 ? Xq : (z == 1 ? Xk : Xv);
  const __bf16* W = Wt + (size_t)z * 1048576;
  const float scale = z == 0 ? 0.125f * 1.44269504088896f : 1.f;
  const int t = threadIdx.x;
  const int lane = t & 63, w = t >> 6;
  const int lane15 = lane & 15, quad = lane >> 4;
  const int wm = (w >> 1) * 64, wn = (w & 1) * 64;
  const int mBase = blockIdx.y * 128, nBase = blockIdx.x * 128;
  const int c1 = t, c2 = t + 256;
  f32x4 acc[4][4] = {};
  for (int kt = 0; kt < 1024; kt += 32) {
    __syncthreads();
    g2l16(X + (size_t)(mBase + (c1 >> 2)) * 1024 + kt + (c1 & 3) * 8, As + c1 * 8);
    g2l16(X + (size_t)(mBase + (c2 >> 2)) * 1024 + kt + (c2 & 3) * 8, As + c2 * 8);
    g2l16(W + (size_t)(nBase + (c1 >> 2)) * 1024 + kt + (c1 & 3) * 8, Bs + c1 * 8);
    g2l16(W + (size_t)(nBase + (c2 >> 2)) * 1024 + kt + (c2 & 3) * 8, Bs + c2 * 8);
    __builtin_amdgcn_s_waitcnt(0);
    __syncthreads();
    bf16x8 a[4], b[4];
#pragma unroll
    for (int i = 0; i < 4; i++) a[i] = *(const bf16x8*)&As[(wm + i * 16 + lane15) * 32 + quad * 8];
#pragma unroll
    for (int j = 0; j < 4; j++) b[j] = *(const bf16x8*)&Bs[(wn + j * 16 + lane15) * 32 + quad * 8];
#pragma unroll
    for (int i = 0; i < 4; i++)
#pragma unroll
      for (int j = 0; j < 4; j++)
        acc[i][j] = MFMA16(a[i], b[j], acc[i][j]);
  }
  if (z != 2) {
    __bf16* Y = z == 0 ? Qb : Kb;
#pragma unroll
    for (int i = 0; i < 4; i++)
#pragma unroll
      for (int j = 0; j < 4; j++)
#pragma unroll
        for (int r = 0; r < 4; r++) {
          int mg = mBase + wm + i * 16 + quad * 4 + r;
          int ng = nBase + wn + j * 16 + lane15;
          int b_ = mg >> 11, s_ = mg & 2047, h_ = ng >> 6, d_ = ng & 63;
          Y[(((size_t)(b_ * 16 + h_)) * 2048 + s_) * 64 + d_] = (__bf16)(acc[i][j][r] * scale);
        }
  } else {
    const int s0 = mBase & 2047;
    const int bhBase = (mBase >> 11) * 16 + (nBase >> 6);
#pragma unroll
    for (int half = 0; half < 2; ++half) {
      __syncthreads();
      if ((w & 1) == half) {
#pragma unroll
        for (int i = 0; i < 4; i++)
#pragma unroll
          for (int j = 0; j < 4; j++)
#pragma unroll
            for (int r = 0; r < 4; r++) {
              int nl = j * 16 + lane15;
              int ml = wm + i * 16 + quad * 4 + r;
              // within-32 t-permutation to match attn's in-register P fragment
              int l5 = ml & 31;
              int mlp = (ml & 96) | ((((l5 >> 2) & 3) * 8) + ((l5 & 3) * 2) + ((l5 >> 4) & 1));
              sh[nl * 128 + (mlp ^ ((nl & 7) * 16))] = (__bf16)acc[i][j][r];
            }
      }
      __syncthreads();
      const int row = t >> 2, c0 = (t & 3) * 32;
      const int xr = (row & 7) * 16;
      const int b0 = row * 128 + (c0 ^ xr);
      const int b1 = row * 128 + ((c0 + 16) ^ xr);
      bf16x8 a0 = *(const bf16x8*)&sh[b0];
      bf16x8 a1 = *(const bf16x8*)&sh[b0 + 8];
      bf16x8 a2 = *(const bf16x8*)&sh[b1];
      bf16x8 a3 = *(const bf16x8*)&sh[b1 + 8];
      __bf16* dst = Vtb + (size_t)(bhBase + half) * 131072 + (size_t)row * 2048 + s0 + c0;
      *(bf16x8*)(dst)      = a0;
      *(bf16x8*)(dst + 8)  = a1;
      *(bf16x8*)(dst + 16) = a2;
      *(bf16x8*)(dst + 24) = a3;
    }
  }
}

// ---------------- output projection + fp32 residual, 64x128 tile ----------------
__global__ __launch_bounds__(256) void gemm_wo(const __bf16* __restrict__ X,
    const __bf16* __restrict__ Wt, const float* __restrict__ resid,
    float* __restrict__ Yf) {
  __shared__ __align__(16) __bf16 As[64 * 32];
  __shared__ __align__(16) __bf16 Bs[128 * 32];
  const int t = threadIdx.x;
  const int lane = t & 63, w = t >> 6;
  const int lane15 = lane & 15, quad = lane >> 4;
  const int wm = (w >> 1) * 32, wn = (w & 1) * 64;
  const int mBase = blockIdx.y * 64, nBase = blockIdx.x * 128;
  f32x4 acc[2][4] = {};
  for (int kt = 0; kt < 1024; kt += 32) {
    __syncthreads();
    g2l16(X  + (size_t)(mBase + (t >> 2)) * 1024 + kt + (t & 3) * 8, As + t * 8);
    g2l16(Wt + (size_t)(nBase + (t >> 2)) * 1024 + kt + (t & 3) * 8, Bs + t * 8);
    g2l16(Wt + (size_t)(nBase + ((t + 256) >> 2)) * 1024 + kt + (t & 3) * 8, Bs + (t + 256) * 8);
    __builtin_amdgcn_s_waitcnt(0);
    __syncthreads();
    bf16x8 a[2], b[4];
#pragma unroll
    for (int i = 0; i < 2; i++) a[i] = *(const bf16x8*)&As[(wm + i * 16 + lane15) * 32 + quad * 8];
#pragma unroll
    for (int j = 0; j < 4; j++) b[j] = *(const bf16x8*)&Bs[(wn + j * 16 + lane15) * 32 + quad * 8];
#pragma unroll
    for (int i = 0; i < 2; i++)
#pragma unroll
      for (int j = 0; j < 4; j++)
        acc[i][j] = MFMA16(a[i], b[j], acc[i][j]);
  }
#pragma unroll
  for (int i = 0; i < 2; i++)
#pragma unroll
    for (int j = 0; j < 4; j++)
#pragma unroll
      for (int r = 0; r < 4; r++) {
        int mg = mBase + wm + i * 16 + quad * 4 + r;
        int ng = nBase + wn + j * 16 + lane15;
        size_t idx = (size_t)mg * 1024 + ng;
        Yf[idx] = acc[i][j][r] + resid[idx];
      }
}

// ---------------- flash attention: 16x16, t-tile 32, 3-stage pipeline, 4x unroll ----------------
// Round-6 verified structure (60.4us) + T5 s_setprio around MFMA clusters.
// XCD swizzle: all 32 q-blocks of one bh share one XCD -> K/V L2-resident (FETCH 14MB).
// Pipeline (iter n): QK(n) from kreg | exp2(st(n-1)) -> pa(n-1) | PV(n-2) from pa/vreg |
// prefetch kreg(n+1), vreg(n-1) from LDS.
// 4x unroll: LDS slot indices are macro-literal constants -> ds ops use immediate offsets.
// exp2 = raw v_exp_f32. All register buffers parity-named (rule #20; r7 lesson: 2-tile
// state ~180 VGPR does NOT fit the 128 cap -> spill catastrophe. Keep 1-tile state.)
__global__ __launch_bounds__(256, 4) void attn_kernel(const __bf16* __restrict__ Q,
    const __bf16* __restrict__ Kp, const __bf16* __restrict__ Vt,
    const unsigned* __restrict__ mbits, __bf16* __restrict__ ctx) {
  __shared__ __align__(16) __bf16 Qs[64 * 64];     // 8KB [q][dk]
  __shared__ __align__(16) __bf16 Ks[4][32 * 64];  // 16KB [t][dk]
  __shared__ __align__(16) __bf16 Vs[4][64 * 32];  // 16KB [d][t-permuted]
  const int t = threadIdx.x, lane = t & 63, w = t >> 6;
  const int l15 = lane & 15, quad = lane >> 4;
  // XCD-aware swizzle: id%8 = XCD; give each XCD 4 whole bh's (32 q-tiles each)
  const int id = blockIdx.x + (blockIdx.y << 5);
  const int iix = id >> 3;
  const int bh = (id & 7) * 4 + (iix >> 5);
  const int qBase = (iix & 31) * 64;
  const int b = bh >> 4, h = bh & 15;
  const size_t qko = (size_t)bh * 2048 * 64;
  const size_t vko = (size_t)bh * 64 * 2048;
  const int srow8 = lane >> 3, sch8 = (lane & 7) ^ srow8;
  const int srow16 = lane >> 2, sch4 = (lane & 3) ^ ((lane >> 3) & 3);
  const int stOff = w * 512 + lane * 8;
  const __bf16* kSrc = Kp + qko + (size_t)(w * 8 + srow8) * 64 + sch8 * 8;
  const __bf16* vSrc = Vt + vko + (size_t)(w * 16 + srow16) * 2048 + sch4 * 8;
  __bf16* KsF = &Ks[0][0];
  __bf16* VsF = &Vs[0][0];
  g2l16(Q + qko + (size_t)(qBase + w * 8 + srow8) * 64 + sch8 * 8,       Qs + w * 512 + lane * 8);
  g2l16(Q + qko + (size_t)(qBase + (w + 4) * 8 + srow8) * 64 + sch8 * 8, Qs + (w + 4) * 512 + lane * 8);
  g2l16(kSrc,        KsF + stOff);
  g2l16(vSrc,        VsF + stOff);
  g2l16(kSrc + 2048, KsF + 2048 + stOff);
  g2l16(vSrc + 32,   VsF + 2048 + stOff);
  const __bf16* kStage = kSrc + 2 * 2048;
  const __bf16* vStage = vSrc + 2 * 32;
  const size_t mIdx = ((size_t)b * 2048 + qBase + w * 16 + l15) * 64;
  unsigned mCur = mbits[mIdx];   // mask tile 0
  unsigned mPrev = 0;
  __builtin_amdgcn_s_waitcnt(0);
  __syncthreads();
  bf16x8 qb0, qb1;
  {
    const int r = w * 16 + l15, s = r & 7;
    qb0 = *(const bf16x8*)&Qs[r * 64 + ((quad ^ s) * 8)];
    qb1 = *(const bf16x8*)&Qs[r * 64 + (((4 + quad) ^ s) * 8)];
  }
  // per-thread LDS fragment base pointers (slot selected via constant immediate offset)
  const int sA = l15 & 7, trB = 16 + l15, sB = trB & 7;
  const __bf16* pKA0 = KsF + l15 * 64 + ((quad ^ sA) * 8);
  const __bf16* pKA1 = KsF + l15 * 64 + (((4 + quad) ^ sA) * 8);
  const __bf16* pKB0 = KsF + trB * 64 + ((quad ^ sB) * 8);
  const __bf16* pKB1 = KsF + trB * 64 + (((4 + quad) ^ sB) * 8);
  const int dr0 = l15,      dr1 = 16 + l15, dr2 = 32 + l15, dr3 = 48 + l15;
  const __bf16* pV0 = VsF + dr0 * 32 + ((quad ^ ((dr0 >> 1) & 3)) * 8);
  const __bf16* pV1 = VsF + dr1 * 32 + ((quad ^ ((dr1 >> 1) & 3)) * 8);
  const __bf16* pV2 = VsF + dr2 * 32 + ((quad ^ ((dr2 >> 1) & 3)) * 8);
  const __bf16* pV3 = VsF + dr3 * 32 + ((quad ^ ((dr3 >> 1) & 3)) * 8);
  bf16x8 krA[2][2], krB[2][2];   // [j][dk-half], parity-named
  krA[0][0] = *(const bf16x8*)(pKA0);
  krA[0][1] = *(const bf16x8*)(pKA1);
  krA[1][0] = *(const bf16x8*)(pKB0);
  krA[1][1] = *(const bf16x8*)(pKB1);
  bf16x8 ones;
#pragma unroll
  for (int i = 0; i < 8; i++) ones[i] = (__bf16)1.0f;
  f32x4 o[4] = {};
  f32x4 ol = {};
  f32x4 stA[2] = {}, stB[2] = {};
  bf16x8 paA = {}, paB = {};
  bf16x8 vrA[4] = {}, vrB[4] = {};

// SLS/SLK/SLV are literal slot constants: stage=(c+2)&3, kreg=(c+1)&3, vreg=(c+3)&3
#define ATTN_BODY(KT, SLS, SLK, SLV, KC, KN, STO, STI, PAO, PAI, VRO, VRI)          \
  {                                                                                 \
    __syncthreads(); /* tile (KT)+1 staged; K(KT) already in regs */                \
    if ((KT) < 62) {                                                                \
      g2l16(kStage, KsF + (SLS) * 2048 + stOff); kStage += 2048;                    \
      g2l16(vStage, VsF + (SLS) * 2048 + stOff); vStage += 32;                      \
    }                                                                               \
    unsigned mNew = 0;                                                              \
    if ((KT) < 63) mNew = mbits[mIdx + (KT) + 1];                                   \
    /* QK(KT) from registers: lane holds q=l15, t = j*16 + quad*4 + r */            \
    __builtin_amdgcn_s_setprio(1);                                                  \
    {                                                                               \
      f32x4 zz = {0.f, 0.f, 0.f, 0.f};                                              \
      zz     = MFMA16(KC[0][0], qb0, zz);                                           \
      STO[0] = MFMA16(KC[0][1], qb1, zz);                                           \
      f32x4 zy = {0.f, 0.f, 0.f, 0.f};                                              \
      zy     = MFMA16(KC[1][0], qb0, zy);                                           \
      STO[1] = MFMA16(KC[1][1], qb1, zy);                                           \
    }                                                                               \
    /* PV(KT-2): pa and V-frags both from registers */                              \
    if ((KT) >= 2) {                                                                \
      ol   = MFMA16(PAI, ones,   ol);                                               \
      o[0] = MFMA16(PAI, VRI[0], o[0]);                                             \
      o[1] = MFMA16(PAI, VRI[1], o[1]);                                             \
      o[2] = MFMA16(PAI, VRI[2], o[2]);                                             \
      o[3] = MFMA16(PAI, VRI[3], o[3]);                                             \
    }                                                                               \
    __builtin_amdgcn_s_setprio(0);                                                  \
    /* prefetch kreg(KT+1): constant slot -> immediate ds offsets */                \
    if ((KT) < 63) {                                                                \
      KN[0][0] = *(const bf16x8*)(pKA0 + (SLK) * 2048);                             \
      KN[0][1] = *(const bf16x8*)(pKA1 + (SLK) * 2048);                             \
      KN[1][0] = *(const bf16x8*)(pKB0 + (SLK) * 2048);                             \
      KN[1][1] = *(const bf16x8*)(pKB1 + (SLK) * 2048);                             \
    }                                                                               \
    /* prefetch vreg(KT-1): constant slot -> immediate ds offsets */                \
    if ((KT) >= 1) {                                                                \
      VRO[0] = *(const bf16x8*)(pV0 + (SLV) * 2048);                                \
      VRO[1] = *(const bf16x8*)(pV1 + (SLV) * 2048);                                \
      VRO[2] = *(const bf16x8*)(pV2 + (SLV) * 2048);                                \
      VRO[3] = *(const bf16x8*)(pV3 + (SLV) * 2048);                                \
    }                                                                               \
    /* exp2(st(KT-1)) -> pa(KT-1); raw v_exp_f32; mask via packed 16-bit sign */    \
    if ((KT) >= 1) {                                                                \
      const unsigned msh = mPrev >> (quad * 4);                                     \
      union { unsigned u[4]; bf16x8 v; } pk;                                        \
      _Pragma("unroll")                                                             \
      for (int r = 0; r < 4; r++) {                                                 \
        float e0 = __builtin_amdgcn_exp2f(STI[0][r]);                               \
        float e1 = __builtin_amdgcn_exp2f(STI[1][r]);                               \
        union { unsigned u; s16x2 s; } mc;                                          \
        mc.u = msh << (15 - r);                                                     \
        mc.s = mc.s >> 15;                                                          \
        pk.u[r] = pack_bf16(e0, e1) & mc.u;                                         \
      }                                                                             \
      PAO = pk.v;                                                                   \
    }                                                                               \
    mPrev = mCur; mCur = mNew;                                                      \
  }

  for (int kt = 0; kt < 64; kt += 4) {
    ATTN_BODY(kt + 0, 2, 1, 3, krA, krB, stA, stB, paB, paA, vrB, vrA);
    ATTN_BODY(kt + 1, 3, 2, 0, krB, krA, stB, stA, paA, paB, vrA, vrB);
    ATTN_BODY(kt + 2, 0, 3, 1, krA, krB, stA, stB, paB, paA, vrB, vrA);
    ATTN_BODY(kt + 3, 1, 0, 2, krB, krA, stB, stA, paA, paB, vrA, vrB);
  }
#undef ATTN_BODY

  // epilogue: vreg(63), PV(62), exp2(st(63)) -> pa(63), PV(63)
  {
    // slot of tile 63 = 3; no further writes
    vrB[0] = *(const bf16x8*)(pV0 + 3 * 2048);
    vrB[1] = *(const bf16x8*)(pV1 + 3 * 2048);
    vrB[2] = *(const bf16x8*)(pV2 + 3 * 2048);
    vrB[3] = *(const bf16x8*)(pV3 + 3 * 2048);
    // PV(62): pa(62)=paA (built at kt=63), vreg(62)=vrA (prefetched at kt=63)
    __builtin_amdgcn_s_setprio(1);
    ol   = MFMA16(paA, ones,   ol);
    o[0] = MFMA16(paA, vrA[0], o[0]);
    o[1] = MFMA16(paA, vrA[1], o[1]);
    o[2] = MFMA16(paA, vrA[2], o[2]);
    o[3] = MFMA16(paA, vrA[3], o[3]);
    __builtin_amdgcn_s_setprio(0);
    // exp2(st(63)=stB) with mask(63)=mPrev
    const unsigned msh = mPrev >> (quad * 4);
    union { unsigned u[4]; bf16x8 v; } pk;
#pragma unroll
    for (int r = 0; r < 4; r++) {
      float e0 = __builtin_amdgcn_exp2f(stB[0][r]);
      float e1 = __builtin_amdgcn_exp2f(stB[1][r]);
      union { unsigned u; s16x2 s; } mc;
      mc.u = msh << (15 - r);
      mc.s = mc.s >> 15;
      pk.u[r] = pack_bf16(e0, e1) & mc.u;
    }
    paB = pk.v;
    // PV(63)
    __builtin_amdgcn_s_setprio(1);
    ol   = MFMA16(paB, ones,   ol);
    o[0] = MFMA16(paB, vrB[0], o[0]);
    o[1] = MFMA16(paB, vrB[1], o[1]);
    o[2] = MFMA16(paB, vrB[2], o[2]);
    o[3] = MFMA16(paB, vrB[3], o[3]);
    __builtin_amdgcn_s_setprio(0);
  }
#pragma unroll
  for (int r = 0; r < 4; r++) {
    float inv = 1.f / ol[r];
    int qg = qBase + w * 16 + quad * 4 + r;
    size_t base = ((size_t)b * 2048 + qg) * 1024 + h * 64;
#pragma unroll
    for (int j = 0; j < 4; j++)
      ctx[base + j * 16 + l15] = (__bf16)(o[j][r] * inv);
  }
}

// ---------------- LayerNorm over D=1024 per row (fp32) ----------------
__global__ __launch_bounds__(256) void ln_kernel(const float* __restrict__ X,
    const float* __restrict__ gamma, const float* __restrict__ beta,
    float* __restrict__ out) {
  __shared__ float red[8];
  const int t = threadIdx.x;
  const size_t row = blockIdx.x;
  const float* xr = X + row * 1024;
  float4 x = *(const float4*)(xr + t * 4);
  float s = x.x + x.y + x.z + x.w;
  float s2 = x.x * x.x + x.y * x.y + x.z * x.z + x.w * x.w;
#pragma unroll
  for (int off = 1; off < 64; off <<= 1) { s += __shfl_xor(s, off); s2 += __shfl_xor(s2, off); }
  if ((t & 63) == 0) { red[t >> 6] = s; red[4 + (t >> 6)] = s2; }
  __syncthreads();
  float S1 = red[0] + red[1] + red[2] + red[3];
  float S2 = red[4] + red[5] + red[6] + red[7];
  float mu = S1 * (1.f / 1024.f);
  float var = S2 * (1.f / 1024.f) - mu * mu;
  float rs = rsqrtf(var + 1e-5f);
  float4 g = *(const float4*)(gamma + t * 4);
  float4 bb = *(const float4*)(beta + t * 4);
  float4 y;
  y.x = (x.x - mu) * rs * g.x + bb.x;
  y.y = (x.y - mu) * rs * g.y + bb.y;
  y.z = (x.z - mu) * rs * g.z + bb.z;
  y.w = (x.w - mu) * rs * g.w + bb.w;
  *(float4*)(out + row * 1024 + t * 4) = y;
}

extern "C" void kernel_launch(void* const* d_in, const int* in_sizes, int n_in,
                              void* d_out, int out_size, void* d_ws, size_t ws_size,
                              hipStream_t stream) {
  const float* inQ  = (const float*)d_in[0];
  const float* inK  = (const float*)d_in[1];
  const float* inV  = (const float*)d_in[2];
  const int*   mask = (const int*)d_in[3];
  const float* WQ   = (const float*)d_in[4];
  const float* WK   = (const float*)d_in[5];
  const float* WV   = (const float*)d_in[6];
  const float* WO   = (const float*)d_in[7];
  const float* gamma = (const float*)d_in[8];
  const float* beta  = (const float*)d_in[9];

  const size_t MB = 1024 * 1024;
  char* ws = (char*)d_ws;
  __bf16* Xq  = (__bf16*)(ws);                    // 8 MB each
  __bf16* Xk  = (__bf16*)(ws + 8 * MB);
  __bf16* Xv  = (__bf16*)(ws + 16 * MB);
  __bf16* Qb  = (__bf16*)(ws + 24 * MB);          // [BH][S][DK]
  __bf16* Kb  = (__bf16*)(ws + 32 * MB);
  __bf16* Vtb = (__bf16*)(ws + 48 * MB);          // [BH][DK][S] (t-permuted per 32)
  __bf16* Wt  = (__bf16*)(ws + 56 * MB);          // 4x 2MB bf16^T weights
  unsigned long long* mbits = (unsigned long long*)(ws + 64 * MB);  // 1 MB (KEEP bits)
  __bf16* ctx  = Xq;                              // reuse
  float*  outp = (float*)(ws + 8 * MB);           // reuse Xk+Xv

  prep<<<dim3(11264), 256, 0, stream>>>(inQ, inK, inV, mask, WQ, WK, WV, WO,
                                        Xq, Xk, Xv, mbits, Wt);
  qkv_gemm<<<dim3(8, 32, 3), 256, 0, stream>>>(Xq, Xk, Xv, Wt, Qb, Kb, Vtb);
  attn_kernel<<<dim3(32, 32), 256, 0, stream>>>(Qb, Kb, Vtb, (const unsigned*)mbits, ctx);
  gemm_wo<<<dim3(8, 64), 256, 0, stream>>>(ctx, Wt + 3 * 1048576, inQ, outp);
  ln_kernel<<<dim3(4096), 256, 0, stream>>>(outp, gamma, beta, (float*)d_out);
}